// Round 6
// baseline (829.874 us; speedup 1.0000x reference)
//
#include <hip/hip_runtime.h>
#include <math.h>

#define NN   100000
#define HH   128
#define INF_ 35
#define GG   1000
#define LBM  64

static __device__ __forceinline__ float silu_f(float x){ return x / (1.f + __expf(-x)); }
#define BN_INV 0.9999950000374997f  /* 1/sqrt(1+1e-5) */

// ---------------- stacked CSR build (both graphs, dst' = dst + n*branch) ----------------
__global__ void k_count(const int* __restrict__ ei1, const int* __restrict__ ei2,
                        int E1, int E2, int n, int* __restrict__ deg){
    int e = blockIdx.x*256 + threadIdx.x;
    int ET = E1 + E2;
    if (e >= ET) return;
    int c;
    if (e < E1) c = ei1[E1 + e];
    else        c = n + ei2[E2 + (e - E1)];
    atomicAdd(&deg[c], 1);
}

__global__ void k_scan1(const int* __restrict__ deg, int n2, int* __restrict__ off, int* __restrict__ bsum){
    __shared__ int s[256];
    int tid = threadIdx.x; int i = blockIdx.x*256 + tid;
    int v = (i<n2)? deg[i] : 0;
    s[tid] = v; __syncthreads();
    for (int ofs=1; ofs<256; ofs<<=1){
        int t = (tid>=ofs)? s[tid-ofs] : 0;
        __syncthreads(); s[tid] += t; __syncthreads();
    }
    if (i<n2) off[i] = s[tid] - v;
    if (tid==255) bsum[blockIdx.x] = s[255];
}

__global__ void k_scan2(int* __restrict__ bsum, int nb){
    __shared__ int s[1024];
    int tid = threadIdx.x;
    int v = (tid<nb)? bsum[tid] : 0;
    s[tid] = v; __syncthreads();
    for (int ofs=1; ofs<1024; ofs<<=1){
        int t = (tid>=ofs)? s[tid-ofs] : 0;
        __syncthreads(); s[tid] += t; __syncthreads();
    }
    if (tid<nb) bsum[tid] = s[tid] - v;
}

__global__ void k_scan3(int* __restrict__ off, const int* __restrict__ bsum, int n2, int ET){
    int i = blockIdx.x*256 + threadIdx.x;
    if (i<n2) off[i] += bsum[i>>8];
    if (i==0) off[n2] = ET;
}

// fill stacked CSR records: {rb[0..8], src, d, pad} = 48B
__global__ void k_fill(const int* __restrict__ ei1, const int* __restrict__ ei2,
                       int E1, int E2, int n, const float* __restrict__ pos,
                       const int* __restrict__ off, int* __restrict__ cur,
                       float4* __restrict__ rec){
    int e = blockIdx.x*256 + threadIdx.x;
    int ET = E1 + E2;
    if (e >= ET) return;
    int r, creal, cslot;
    if (e < E1){ r = ei1[e];        creal = ei1[E1 + e];        cslot = creal; }
    else       { int ee = e - E1; r = ei2[ee]; creal = ei2[E2 + ee]; cslot = n + creal; }
    int slot = atomicAdd(&cur[cslot], 1);
    int p = off[cslot] + slot;
    float dx = pos[r*3+0]-pos[creal*3+0];
    float dy = pos[r*3+1]-pos[creal*3+1];
    float dz = pos[r*3+2]-pos[creal*3+2];
    float d  = sqrtf(dx*dx + dy*dy + dz*dz);
    float rb[9];
    #pragma unroll
    for (int k=0;k<9;k++){
        float t = (d - 0.75f*(float)k) * 1.5f;
        rb[k] = __expf(-t*t);
    }
    rec[(size_t)p*3+0] = make_float4(rb[0],rb[1],rb[2],rb[3]);
    rec[(size_t)p*3+1] = make_float4(rb[4],rb[5],rb[6],rb[7]);
    rec[(size_t)p*3+2] = make_float4(rb[8], __int_as_float(r), d, 0.f);
}

// ---------------- input: h = silu(x @ W_in + b) ----------------
#define NT_IN (NN/16)
__global__ __launch_bounds__(256) void k_input(const float* __restrict__ x, const float* __restrict__ W,
                        const float* __restrict__ b, float* __restrict__ h){
    __shared__ __align__(16) float xs[16][36];
    int tx = threadIdx.x;
    int c = tx & 127, g = tx >> 7;
    float4 wv[9];
    {
        float* wf = (float*)wv;
        #pragma unroll
        for (int k=0;k<INF_;k++) wf[k] = W[k*HH + c];
        wf[35] = 0.f;
    }
    float bc = b[c];
    for (int tile = blockIdx.x; tile < NT_IN; tile += gridDim.x){
        int r0 = tile*16;
        for (int i = tx; i < 16*INF_; i += 256){
            int rr = i/INF_, kk = i - rr*INF_;
            xs[rr][kk] = x[(size_t)(r0+rr)*INF_ + kk];
        }
        if (tx < 16) xs[tx][35] = 0.f;
        __syncthreads();
        float acc[8];
        #pragma unroll
        for (int j=0;j<8;j++) acc[j] = bc;
        #pragma unroll
        for (int kk=0;kk<9;kk++){
            float4 w4 = wv[kk];
            #pragma unroll
            for (int j=0;j<8;j++){
                float4 xv = *(const float4*)(&xs[g*8+j][kk*4]);
                acc[j] += xv.x*w4.x + xv.y*w4.y + xv.z*w4.z + xv.w*w4.w;
            }
        }
        #pragma unroll
        for (int j=0;j<8;j++){
            int gr = r0 + g*8 + j;
            h[(size_t)gr*HH + c] = silu_f(acc[j]);
        }
        __syncthreads();
    }
}

// ---------------- fused per-layer: gather(+radial) -> LDS -> GEMM -> BN -> h_new ----------------
#define QPAIR(A0,A1,A2X,Q0,Q1)              \
    float Q0 = cb.x, Q1 = cb.y;             \
    Q0 += A0.x*w0[0]; Q1 += A0.x*w1[0];     \
    Q0 += A0.y*w0[1]; Q1 += A0.y*w1[1];     \
    Q0 += A0.z*w0[2]; Q1 += A0.z*w1[2];     \
    Q0 += A0.w*w0[3]; Q1 += A0.w*w1[3];     \
    Q0 += A1.x*w0[4]; Q1 += A1.x*w1[4];     \
    Q0 += A1.y*w0[5]; Q1 += A1.y*w1[5];     \
    Q0 += A1.z*w0[6]; Q1 += A1.z*w1[6];     \
    Q0 += A1.w*w0[7]; Q1 += A1.w*w1[7];     \
    Q0 += A2X*w0[8];  Q1 += A2X*w1[8];

#define GSTEP(K, BV, ACC) {                                                   \
    float4 a0 = *(const float4*)(&As[K][r0g]);                                \
    float4 a1 = *(const float4*)(&As[K][r0g+4]);                              \
    ACC[0][0]+=a0.x*BV.x; ACC[0][1]+=a0.x*BV.y; ACC[0][2]+=a0.x*BV.z; ACC[0][3]+=a0.x*BV.w; \
    ACC[1][0]+=a0.y*BV.x; ACC[1][1]+=a0.y*BV.y; ACC[1][2]+=a0.y*BV.z; ACC[1][3]+=a0.y*BV.w; \
    ACC[2][0]+=a0.z*BV.x; ACC[2][1]+=a0.z*BV.y; ACC[2][2]+=a0.z*BV.z; ACC[2][3]+=a0.z*BV.w; \
    ACC[3][0]+=a0.w*BV.x; ACC[3][1]+=a0.w*BV.y; ACC[3][2]+=a0.w*BV.z; ACC[3][3]+=a0.w*BV.w; \
    ACC[4][0]+=a1.x*BV.x; ACC[4][1]+=a1.x*BV.y; ACC[4][2]+=a1.x*BV.z; ACC[4][3]+=a1.x*BV.w; \
    ACC[5][0]+=a1.y*BV.x; ACC[5][1]+=a1.y*BV.y; ACC[5][2]+=a1.y*BV.z; ACC[5][3]+=a1.y*BV.w; \
    ACC[6][0]+=a1.z*BV.x; ACC[6][1]+=a1.z*BV.y; ACC[6][2]+=a1.z*BV.z; ACC[6][3]+=a1.z*BV.w; \
    ACC[7][0]+=a1.w*BV.x; ACC[7][1]+=a1.w*BV.y; ACC[7][2]+=a1.w*BV.z; ACC[7][3]+=a1.w*BV.w; }

#define PHASE(BRN, ACC, CWP, CBP, BMATP) {                                    \
    float w0[9], w1[9];                                                       \
    _Pragma("unroll")                                                         \
    for (int k=0;k<9;k++){                                                    \
        float2 t = *(const float2*)((CWP) + k*HH + c2);                       \
        w0[k]=t.x; w1[k]=t.y;                                                 \
    }                                                                         \
    float2 cb = *(const float2*)((CBP) + c2);                                 \
    for (int i=0;i<16;i++){                                                   \
        int node = rb + wv*16 + i;                                            \
        if (node < n){                                                        \
            float2 acc = *(const float2*)(h + (size_t)node*HH + c2);          \
            int lo = off[node + (BRN)*n], hi = off[node + (BRN)*n + 1];       \
            lo = __builtin_amdgcn_readfirstlane(lo);                          \
            hi = __builtin_amdgcn_readfirstlane(hi);                          \
            const float4* rp = rec + (size_t)lo*3;                            \
            int p = lo;                                                       \
            for (; p+4<=hi; p+=4, rp+=12){                                    \
                float4 e0a = rp[0],  e0b = rp[1],  e0c = rp[2];               \
                float4 e1a = rp[3],  e1b = rp[4],  e1c = rp[5];               \
                float4 e2a = rp[6],  e2b = rp[7],  e2c = rp[8];               \
                float4 e3a = rp[9],  e3b = rp[10], e3c = rp[11];              \
                int s0 = __float_as_int(e0c.y); int s1 = __float_as_int(e1c.y); \
                int s2 = __float_as_int(e2c.y); int s3 = __float_as_int(e3c.y); \
                float2 hv0 = *(const float2*)(h + (size_t)s0*HH + c2);        \
                float2 hv1 = *(const float2*)(h + (size_t)s1*HH + c2);        \
                float2 hv2 = *(const float2*)(h + (size_t)s2*HH + c2);        \
                float2 hv3 = *(const float2*)(h + (size_t)s3*HH + c2);        \
                QPAIR(e0a, e0b, e0c.x, q00, q01)                              \
                QPAIR(e1a, e1b, e1c.x, q10, q11)                              \
                QPAIR(e2a, e2b, e2c.x, q20, q21)                              \
                QPAIR(e3a, e3b, e3c.x, q30, q31)                              \
                acc.x += hv0.x * silu_f(q00); acc.y += hv0.y * silu_f(q01);   \
                acc.x += hv1.x * silu_f(q10); acc.y += hv1.y * silu_f(q11);   \
                acc.x += hv2.x * silu_f(q20); acc.y += hv2.y * silu_f(q21);   \
                acc.x += hv3.x * silu_f(q30); acc.y += hv3.y * silu_f(q31);   \
            }                                                                 \
            for (; p+2<=hi; p+=2, rp+=6){                                     \
                float4 e0a = rp[0], e0b = rp[1], e0c = rp[2];                 \
                float4 e1a = rp[3], e1b = rp[4], e1c = rp[5];                 \
                int s0 = __float_as_int(e0c.y); int s1 = __float_as_int(e1c.y); \
                float2 hv0 = *(const float2*)(h + (size_t)s0*HH + c2);        \
                float2 hv1 = *(const float2*)(h + (size_t)s1*HH + c2);        \
                QPAIR(e0a, e0b, e0c.x, q00, q01)                              \
                QPAIR(e1a, e1b, e1c.x, q10, q11)                              \
                acc.x += hv0.x * silu_f(q00); acc.y += hv0.y * silu_f(q01);   \
                acc.x += hv1.x * silu_f(q10); acc.y += hv1.y * silu_f(q11);   \
            }                                                                 \
            if (p < hi){                                                      \
                float4 e0a = rp[0], e0b = rp[1], e0c = rp[2];                 \
                int s0 = __float_as_int(e0c.y);                               \
                float2 hv0 = *(const float2*)(h + (size_t)s0*HH + c2);        \
                QPAIR(e0a, e0b, e0c.x, q00, q01)                              \
                acc.x += hv0.x * silu_f(q00); acc.y += hv0.y * silu_f(q01);   \
            }                                                                 \
            As[c2][node-rb]   = acc.x;                                        \
            As[c2+1][node-rb] = acc.y;                                        \
        }                                                                     \
    }                                                                         \
    __syncthreads();                                                          \
    {                                                                         \
        const float* Bc = (BMATP) + c0;                                       \
        float4 bva0 = *(const float4*)(Bc + 0*HH);                            \
        float4 bva1 = *(const float4*)(Bc + 1*HH);                            \
        float4 bva2 = *(const float4*)(Bc + 2*HH);                            \
        float4 bva3 = *(const float4*)(Bc + 3*HH);                            \
        for (int kt=0; kt<HH; kt+=8){                                         \
            float4 bvb0 = *(const float4*)(Bc + (kt+4)*HH);                   \
            float4 bvb1 = *(const float4*)(Bc + (kt+5)*HH);                   \
            float4 bvb2 = *(const float4*)(Bc + (kt+6)*HH);                   \
            float4 bvb3 = *(const float4*)(Bc + (kt+7)*HH);                   \
            GSTEP(kt+0, bva0, ACC) GSTEP(kt+1, bva1, ACC)                     \
            GSTEP(kt+2, bva2, ACC) GSTEP(kt+3, bva3, ACC)                     \
            if (kt+8 < HH){                                                   \
                bva0 = *(const float4*)(Bc + (kt+8)*HH);                      \
                bva1 = *(const float4*)(Bc + (kt+9)*HH);                      \
                bva2 = *(const float4*)(Bc + (kt+10)*HH);                     \
                bva3 = *(const float4*)(Bc + (kt+11)*HH);                     \
            }                                                                 \
            GSTEP(kt+4, bvb0, ACC) GSTEP(kt+5, bvb1, ACC)                     \
            GSTEP(kt+6, bvb2, ACC) GSTEP(kt+7, bvb3, ACC)                     \
        }                                                                     \
    }                                                                         \
    __syncthreads();                                                          \
}

__global__ __launch_bounds__(256) void k_layer(
        const float* __restrict__ h, const int* __restrict__ off, const float4* __restrict__ rec,
        const float* __restrict__ cW0, const float* __restrict__ cB0,
        const float* __restrict__ cW1, const float* __restrict__ cB1,
        const float* __restrict__ W1, const float* __restrict__ W2,
        const float* __restrict__ nb1, const float* __restrict__ nb2,
        const float* __restrict__ g1, const float* __restrict__ g2,
        const float* __restrict__ be1, const float* __restrict__ be2,
        float* __restrict__ hout, int n){
    __shared__ __align__(16) float As[HH][LBM+4];   // [k][row], pad 68 -> b128-aligned rows
    int tx = threadIdx.x;
    int rb = blockIdx.x*LBM;
    int wv = tx>>6;
    int c2 = (tx&63)*2;
    int c0 = (tx&31)*4, r0g = (tx>>5)*8;
    float acc1[8][4], acc2[8][4];
    #pragma unroll
    for (int j=0;j<8;j++){
        #pragma unroll
        for (int q=0;q<4;q++){ acc1[j][q]=0.f; acc2[j][q]=0.f; }
    }

    PHASE(0, acc1, cW0, cB0, W1)
    PHASE(1, acc2, cW1, cB1, W2)

    float4 bi1 = *(const float4*)(nb1 + c0);
    float4 ga1 = *(const float4*)(g1  + c0);
    float4 bt1 = *(const float4*)(be1 + c0);
    float4 bi2 = *(const float4*)(nb2 + c0);
    float4 ga2 = *(const float4*)(g2  + c0);
    float4 bt2 = *(const float4*)(be2 + c0);
    #pragma unroll
    for (int j=0;j<8;j++){
        int gr = rb + r0g + j;
        if (gr < n){
            float x0,x1,x2,x3,y0,y1,y2,y3;
            x0 = acc1[j][0]+bi1.x; x1 = acc1[j][1]+bi1.y; x2 = acc1[j][2]+bi1.z; x3 = acc1[j][3]+bi1.w;
            x0 = (x0>=0.f)? x0 : 0.01f*x0;  x1 = (x1>=0.f)? x1 : 0.01f*x1;
            x2 = (x2>=0.f)? x2 : 0.01f*x2;  x3 = (x3>=0.f)? x3 : 0.01f*x3;
            y0 = acc2[j][0]+bi2.x; y1 = acc2[j][1]+bi2.y; y2 = acc2[j][2]+bi2.z; y3 = acc2[j][3]+bi2.w;
            y0 = (y0>=0.f)? y0 : 0.01f*y0;  y1 = (y1>=0.f)? y1 : 0.01f*y1;
            y2 = (y2>=0.f)? y2 : 0.01f*y2;  y3 = (y3>=0.f)? y3 : 0.01f*y3;
            float4 o;
            o.x = (ga1.x*x0 + ga2.x*y0)*BN_INV + bt1.x + bt2.x;
            o.y = (ga1.y*x1 + ga2.y*y1)*BN_INV + bt1.y + bt2.y;
            o.z = (ga1.z*x2 + ga2.z*y2)*BN_INV + bt1.z + bt2.z;
            o.w = (ga1.w*x3 + ga2.w*y3)*BN_INV + bt1.w + bt2.w;
            *(float4*)(hout + (size_t)gr*HH + c0) = o;
        }
    }
}

// ---------------- fused pool + FC x3 + head ----------------
static __device__ __forceinline__ int lower_bound_i(const int* __restrict__ a, int n, int key){
    int lo=0, hi=n;
    while (lo<hi){ int m=(lo+hi)>>1; if (a[m]<key) lo=m+1; else hi=m; }
    return lo;
}
__global__ void k_poolfc(const float* __restrict__ h, const int* __restrict__ batch,
                     const float* __restrict__ fcW, const float* __restrict__ fcB,
                     const float* __restrict__ fbg, const float* __restrict__ fbb,
                     const float* __restrict__ outW, const float* __restrict__ outB,
                     float* __restrict__ out, int n){
    __shared__ float row[HH];
    __shared__ float red[2];
    int g = blockIdx.x, c = threadIdx.x;
    int lo = lower_bound_i(batch, n, g);
    int hi = lower_bound_i(batch, n, g+1);
    float v = 0.f;
    for (int r=lo; r<hi; r++) v += h[(size_t)r*HH + c];
    for (int l=0;l<3;l++){
        row[c] = v; __syncthreads();
        float acc = fcB[l*HH + c];
        const float* W = fcW + (size_t)l*HH*HH;
        #pragma unroll 8
        for (int k=0;k<HH;k++) acc += row[k]*W[k*HH + c];
        acc = (acc>=0.f)? acc : 0.01f*acc;
        v = fbg[l*HH+c]*acc*BN_INV + fbb[l*HH+c];
        __syncthreads();
    }
    float t = v * outW[c];
    #pragma unroll
    for (int o=32;o>0;o>>=1) t += __shfl_down(t, o, 64);
    if ((c&63)==0) red[c>>6] = t;
    __syncthreads();
    if (c==0) out[g] = red[0] + red[1] + outB[0];
}

extern "C" void kernel_launch(void* const* d_in, const int* in_sizes, int n_in,
                              void* d_out, int out_size, void* d_ws, size_t ws_size,
                              hipStream_t stream){
    const float* x      = (const float*)d_in[0];
    const float* pos    = (const float*)d_in[1];
    const float* W_in   = (const float*)d_in[2];
    const float* b_in   = (const float*)d_in[3];
    const float* coordW = (const float*)d_in[4];
    const float* coordB = (const float*)d_in[5];
    const float* nodeW  = (const float*)d_in[6];
    const float* nodeB  = (const float*)d_in[7];
    const float* bnG    = (const float*)d_in[8];
    const float* bnB    = (const float*)d_in[9];
    const float* fcW    = (const float*)d_in[10];
    const float* fcB    = (const float*)d_in[11];
    const float* fcBnG  = (const float*)d_in[12];
    const float* fcBnB  = (const float*)d_in[13];
    const float* outW   = (const float*)d_in[14];
    const float* outB   = (const float*)d_in[15];
    const int* ei1      = (const int*)d_in[16];
    const int* ei2      = (const int*)d_in[17];
    const int* batch    = (const int*)d_in[18];
    const int E1 = in_sizes[16]/2, E2 = in_sizes[17]/2;
    const int n = NN;
    const int n2 = 2*n;
    const int ET = E1 + E2;

    char* w = (char*)d_ws;
    size_t o = 0;
    auto alloc = [&](size_t bytes)->void*{
        void* r = w + o;
        o += (bytes + 255) & ~(size_t)255;
        return r;
    };
    float*  h    = (float*)alloc((size_t)n*HH*4);
    float*  h2   = (float*)alloc((size_t)n*HH*4);
    int*    off  = (int*)alloc((size_t)(n2+1)*4);
    int*    cnt  = (int*)alloc((size_t)n2*4);   // cnt and cur adjacent -> one memset
    int*    cur  = (int*)alloc((size_t)n2*4);
    float4* rec  = (float4*)alloc((size_t)ET*48);
    int*    bsum = (int*)alloc(1024*4);
    (void)ws_size; (void)n_in; (void)out_size;

    int nb2 = (n2+255)/256;

    hipMemsetAsync(cnt, 0, (size_t)2*n2*4, stream);
    k_count<<<(ET+255)/256,256,0,stream>>>(ei1, ei2, E1, E2, n, cnt);
    k_scan1<<<nb2,256,0,stream>>>(cnt, n2, off, bsum);
    k_scan2<<<1,1024,0,stream>>>(bsum, nb2);
    k_scan3<<<nb2,256,0,stream>>>(off, bsum, n2, ET);
    k_fill<<<(ET+255)/256,256,0,stream>>>(ei1, ei2, E1, E2, n, pos, off, cur, rec);

    k_input<<<2048,256,0,stream>>>(x, W_in, b_in, h);

    float* hcur = h;
    float* hoth = h2;
    int nlb = (n + LBM - 1)/LBM;
    for (int l=0; l<3; l++){
        int li0 = l*2, li1 = l*2+1;
        k_layer<<<nlb,256,0,stream>>>(hcur, off, rec,
            coordW + (size_t)li0*9*HH, coordB + (size_t)li0*HH,
            coordW + (size_t)li1*9*HH, coordB + (size_t)li1*HH,
            nodeW + (size_t)li0*HH*HH, nodeW + (size_t)li1*HH*HH,
            nodeB + (size_t)li0*HH,  nodeB + (size_t)li1*HH,
            bnG   + (size_t)li0*HH,  bnG   + (size_t)li1*HH,
            bnB   + (size_t)li0*HH,  bnB   + (size_t)li1*HH,
            hoth, n);
        float* t = hcur; hcur = hoth; hoth = t;
    }

    k_poolfc<<<GG,128,0,stream>>>(hcur, batch, fcW, fcB, fcBnG, fcBnB, outW, outB, (float*)d_out, n);
}